// Round 6
// baseline (32.197 us; speedup 1.0000x reference)
//
#include <hip/hip_runtime.h>
#include <math.h>

#define NRAYS 32768      // 16*64*32
#define NSPH  1024
#define WPB   8          // waves per block
#define SLICE 128        // spheres per wave (wave w: [w*128, w*128+128))
#define TPB   512
#define NBLK  (NRAYS / 64)   // 512 blocks, one 64-ray group each

__global__ __launch_bounds__(TPB, 8) void sphere_kernel(
    const float* __restrict__ rays,
    const float* __restrict__ centers,
    const float* __restrict__ radii,
    float* __restrict__ out)
{
#pragma clang fp contract(off)
    __shared__ float s_min[WPB][64];
    __shared__ int   s_face[WPB][64];

    const int tid  = threadIdx.x;
    const int lane = tid & 63;
    // wave index, provably wave-uniform -> scalar loads for sphere data
    const int w    = __builtin_amdgcn_readfirstlane(tid >> 6);  // 0..7

    const int ray = blockIdx.x * 64 + lane;
    const float2* rp = (const float2*)(rays + ray * 6);
    const float2 q0 = rp[0], q1 = rp[1], q2 = rp[2];
    const float ox = q0.x, oy = q0.y, oz = q1.x;
    const float dx = q1.y, dy = q2.x, dz = q2.y;

    // a = ((dx*dx)+(dy*dy))+(dz*dz) -- numpy 3-elem sum order
    const float a    = ((dx * dx) + (dy * dy)) + (dz * dz);
    const float epsA = 1e-8f * a;      // w >= epsA  <=>  fl(w/a) >= 1e-8 (1-ulp band)
    const float hunA = 100.0f * a;     // deferred: active <=> bw < hunA
    const float INF  = __builtin_inff();
    const float QNAN = __builtin_nanf("");

    float cw   = INF;   // numerator of current min t (u = t*a before rounding)
    int   carg = 0;     // argmin within slice (first occurrence)

    // Wave-uniform sphere data via the scalar path (SGPR constants in the loop).
    const float4* cb4 = (const float4*)(centers + (size_t)w * SLICE * 3);
    const float4* rb4 = (const float4*)(radii + (size_t)w * SLICE);

    // Software-pipelined: group g+1's scalar loads issue while computing group g.
    float4 C0 = cb4[0], C1 = cb4[1], C2 = cb4[2];
    float4 RR = rb4[0];

    for (int g = 0; g < SLICE / 4; ++g) {
        const int gn = (g + 1 < SLICE / 4) ? g + 1 : g;   // clamped prefetch idx
        const float4 nC0 = cb4[3 * gn + 0];
        const float4 nC1 = cb4[3 * gn + 1];
        const float4 nC2 = cb4[3 * gn + 2];
        const float4 nRR = rb4[gn];

        // 4 spheres: interleaved xyz unpack (floats [12g,12g+12))
        const float xs[4] = {C0.x, C0.w, C1.z, C2.y};
        const float ys[4] = {C0.y, C1.x, C1.w, C2.z};
        const float zs[4] = {C0.z, C1.y, C2.x, C2.w};
        const float rs[4] = {RR.x, RR.y, RR.z, RR.w};
#pragma unroll
        for (int j = 0; j < 4; ++j) {
            const float r2 = rs[j] * rs[j];            // == ref's rad*rad
            const float fx = ox - xs[j];
            const float fy = oy - ys[j];
            const float fz = oz - zs[j];
            const float dt = ((dx * fx) + (dy * fy)) + (dz * fz);
            const float cc = (((fx * fx) + (fy * fy)) + (fz * fz)) - r2;
            // d = b^2-4ac = 4*z with identical rounding (power-of-2 scaling)
            const float z  = (dt * dt) - (a * cc);
            // z<=0 -> NaN -> all compares false -> u=INF (== ref's valid mask)
            const float zm = (z > 0.0f) ? z : QNAN;
            const float s  = __builtin_amdgcn_sqrtf(zm);   // raw v_sqrt
            const float w0 = s - dt;        // numerator of larger root
            const float w1 = -(dt + s);     // numerator of smaller root, w1 <= w0
            // smallest root >= eps, else INF (upper window deferred to hunA test)
            const float u  = (w1 >= epsA) ? w1 : ((w0 >= epsA) ? w0 : INF);
            if (u < cw) { cw = u; carg = (g << 2) | j; }   // strict <: first occurrence
        }
        C0 = nC0; C1 = nC1; C2 = nC2; RR = nRR;
    }

    s_min[w][lane]  = cw;
    s_face[w][lane] = ((w & 1) << 7) | carg;   // chunk-LOCAL face index (0..255)
    __syncthreads();

    // Epilogue: wave 0, one lane per ray.
    if (tid < 64) {
        float bw   = INF;
        int   face = -1;
        for (int k = 0; k < WPB; ++k) {
            const float mt = s_min[k][tid];
            if (mt < bw) { bw = mt; face = s_face[k][tid]; }  // k order == chunk order
        }
        // Deferred window test: any in-window u beats every u>=hunA in the min.
        const bool active = bw < hunA;

        // Single IEEE division per ray: best = fl(u*/a) == reference's rounded t.
        const float best = active ? (bw / a) : 100.0f;

        float px = ox + (best * dx);
        float py = oy + (best * dy);
        float pz = oz + (best * dz);

        // reference: idx = clip(face,0,1023), face in [-1,255] (chunk-local bug kept)
        const int gidx = (active && face >= 0) ? face : 0;
        const float cxv = centers[3 * gidx + 0];
        const float cyv = centers[3 * gidx + 1];
        const float czv = centers[3 * gidx + 2];
        const float ddx = px - cxv;
        const float ddy = py - cyv;
        const float ddz = pz - czv;
        float nrm = sqrtf(((ddx * ddx) + (ddy * ddy)) + (ddz * ddz));
        nrm = fmaxf(nrm, 1e-12f);
        const float nx = active ? (ddx / nrm) : 0.0f;
        const float ny = active ? (ddy / nrm) : 0.0f;
        const float nz = active ? (ddz / nrm) : 0.0f;
        px = px + (nx * 1e-5f);
        py = py + (ny * 1e-5f);
        pz = pz + (nz * 1e-5f);

        const int r = blockIdx.x * 64 + tid;
        float* outp = out;                 // p: 3*NRAYS
        float* outn = out + NRAYS * 3;     // n: 3*NRAYS
        float* outd = out + NRAYS * 6;     // best_dists: NRAYS
        float* outa = out + NRAYS * 7;     // out_active: NRAYS

        outp[r * 3 + 0] = px;
        outp[r * 3 + 1] = py;
        outp[r * 3 + 2] = pz;
        outn[r * 3 + 0] = nx;
        outn[r * 3 + 1] = ny;
        outn[r * 3 + 2] = nz;
        outd[r] = best;
        outa[r] = active ? 1.0f : 0.0f;
    }
}

extern "C" void kernel_launch(void* const* d_in, const int* in_sizes, int n_in,
                              void* d_out, int out_size, void* d_ws, size_t ws_size,
                              hipStream_t stream) {
    const float* rays    = (const float*)d_in[0];
    const float* centers = (const float*)d_in[1];
    const float* radii   = (const float*)d_in[2];
    float* out = (float*)d_out;

    dim3 grid(NBLK);     // 512 blocks
    dim3 block(TPB);     // 512 threads = 8 waves
    hipLaunchKernelGGL(sphere_kernel, grid, block, 0, stream,
                       rays, centers, radii, out);
}

// Round 7
// 29.395 us; speedup vs baseline: 1.0953x; 1.0953x over previous
//
#include <hip/hip_runtime.h>
#include <math.h>

#define NRAYS 32768      // 16*64*32
#define NSPH  1024
#define SUBS  16         // subchunks per ray (64 spheres each)
#define PAIRS 32         // sphere-pairs per subchunk
#define RPB   32         // rays per block (2 per thread)
#define RSL   16         // ray slots per block
#define TPB   256
#define NBLK  (NRAYS / RPB)   // 1024 blocks

__global__ __launch_bounds__(256, 4) void sphere_kernel(
    const float* __restrict__ rays,
    const float* __restrict__ centers,
    const float* __restrict__ radii,
    float* __restrict__ out)
{
#pragma clang fp contract(off)
    // Pair-SoA: pair p of sub k: sph[base+2p]=(x0,x1,y0,y1), sph[base+2p+1]=(z0,z1,r2_0,r2_1)
    // sub stride 65 float4 = 1040 B -> the 4 broadcast addresses per wave hit
    // disjoint bank quads (conflict-free).
    __shared__ float4 sph[SUBS * (2 * PAIRS + 1)];   // 16.6 KB
    __shared__ float  s_min[SUBS][RPB];
    __shared__ int    s_face[SUBS][RPB];

    const int tid = threadIdx.x;

    for (int p = tid; p < NSPH / 2; p += TPB) {
        const int g0 = 2 * p, g1 = 2 * p + 1;
        const float x0 = centers[3 * g0 + 0], y0 = centers[3 * g0 + 1], z0 = centers[3 * g0 + 2];
        const float x1 = centers[3 * g1 + 0], y1 = centers[3 * g1 + 1], z1 = centers[3 * g1 + 2];
        const float r0 = radii[g0], r1 = radii[g1];
        const int b4 = (p >> 5) * (2 * PAIRS + 1) + (p & 31) * 2;
        sph[b4 + 0] = make_float4(x0, x1, y0, y1);
        sph[b4 + 1] = make_float4(z0, z1, r0 * r0, r1 * r1);
    }
    __syncthreads();

    const int rl  = tid & (RSL - 1);   // ray slot 0..15
    const int sub = tid >> 4;          // subchunk 0..15
    const int rayA = blockIdx.x * RPB + rl;
    const int rayB = rayA + RSL;

    const float2* rpa = (const float2*)(rays + rayA * 6);
    const float2 a0 = rpa[0], a1 = rpa[1], a2v = rpa[2];
    const float oxA = a0.x, oyA = a0.y, ozA = a1.x;
    const float dxA = a1.y, dyA = a2v.x, dzA = a2v.y;
    const float2* rpb = (const float2*)(rays + rayB * 6);
    const float2 b0 = rpb[0], b1 = rpb[1], b2v = rpb[2];
    const float oxB = b0.x, oyB = b0.y, ozB = b1.x;
    const float dxB = b1.y, dyB = b2v.x, dzB = b2v.y;

    // a = ((dx*dx)+(dy*dy))+(dz*dz) -- numpy 3-elem sum order
    const float aA = ((dxA * dxA) + (dyA * dyA)) + (dzA * dzA);
    const float aB = ((dxB * dxB) + (dyB * dyB)) + (dzB * dzB);
    const float epsA_A = 1e-8f * aA, negEpsA_A = -(1e-8f * aA);
    const float epsA_B = 1e-8f * aB, negEpsA_B = -(1e-8f * aB);
    const float INF = __builtin_inff();

    float cwA = INF, cwB = INF;
    int cargA = 0, cargB = 0;

    const float4* __restrict__ spb = &sph[sub * (2 * PAIRS + 1)];

#define TEST(SX, SY, SZ, R2, IDX)                                              \
    {                                                                          \
        /* ray A */                                                            \
        {                                                                      \
            const float fx = oxA - (SX), fy = oyA - (SY), fz = ozA - (SZ);     \
            const float dt = ((dxA * fx) + (dyA * fy)) + (dzA * fz);           \
            const float cc = (((fx * fx) + (fy * fy)) + (fz * fz)) - (R2);     \
            const float z  = (dt * dt) - (aA * cc);                            \
            const float s  = __builtin_amdgcn_sqrtf(z);  /* NaN if z<0 */      \
            const float sum = dt + s;                                          \
            const float w0  = s - dt;                                          \
            const float u   = (sum <= negEpsA_A) ? -sum : w0;                  \
            const bool  ok  = (u >= epsA_A) && (u < cwA); /* NaN -> false */   \
            cwA   = ok ? u : cwA;                                              \
            cargA = ok ? (IDX) : cargA;                                        \
        }                                                                      \
        /* ray B */                                                            \
        {                                                                      \
            const float fx = oxB - (SX), fy = oyB - (SY), fz = ozB - (SZ);     \
            const float dt = ((dxB * fx) + (dyB * fy)) + (dzB * fz);           \
            const float cc = (((fx * fx) + (fy * fy)) + (fz * fz)) - (R2);     \
            const float z  = (dt * dt) - (aB * cc);                            \
            const float s  = __builtin_amdgcn_sqrtf(z);                        \
            const float sum = dt + s;                                          \
            const float w0  = s - dt;                                          \
            const float u   = (sum <= negEpsA_B) ? -sum : w0;                  \
            const bool  ok  = (u >= epsA_B) && (u < cwB);                      \
            cwB   = ok ? u : cwB;                                              \
            cargB = ok ? (IDX) : cargB;                                        \
        }                                                                      \
    }

#pragma unroll 8
    for (int i = 0; i < PAIRS; ++i) {
        const float4 A = spb[2 * i];       // (x0,x1,y0,y1)
        const float4 B = spb[2 * i + 1];   // (z0,z1,r2_0,r2_1)
        TEST(A.x, A.z, B.x, B.z, 2 * i);
        TEST(A.y, A.w, B.y, B.w, 2 * i + 1);
    }
#undef TEST

    s_min[sub][rl]        = cwA;
    s_face[sub][rl]       = ((sub & 3) << 6) | cargA;  // chunk-LOCAL face (0..255)
    s_min[sub][rl + RSL]  = cwB;
    s_face[sub][rl + RSL] = ((sub & 3) << 6) | cargB;
    __syncthreads();

    // Epilogue: threads 0..31 handle one ray each.
    if (tid < RPB) {
        float bw   = INF;
        int   face = -1;
        for (int k = 0; k < SUBS; ++k) {
            const float mt = s_min[k][tid];
            if (mt < bw) { bw = mt; face = s_face[k][tid]; }  // earlier chunk wins ties
        }

        const int r = blockIdx.x * RPB + tid;
        const float2* rp = (const float2*)(rays + r * 6);
        const float2 q0 = rp[0], q1 = rp[1], q2 = rp[2];
        const float ox = q0.x, oy = q0.y, oz = q1.x;
        const float dx = q1.y, dy = q2.x, dz = q2.y;
        const float a  = ((dx * dx) + (dy * dy)) + (dz * dz);
        const float hunA = 100.0f * a;

        // Deferred window test: any in-window u beats every u>=hunA in the min.
        const bool active = bw < hunA;

        // Single IEEE division per ray: best = fl(u*/a) == reference's rounded t.
        const float best = active ? (bw / a) : 100.0f;

        float px = ox + (best * dx);
        float py = oy + (best * dy);
        float pz = oz + (best * dz);

        // reference: idx = clip(face,0,1023), face in [-1,255] (chunk-local bug kept)
        const int gidx = face < 0 ? 0 : face;
        const int b4 = (gidx >> 6) * (2 * PAIRS + 1) + ((gidx & 63) >> 1) * 2;
        const int j  = gidx & 1;
        const float4 A = sph[b4];
        const float4 B = sph[b4 + 1];
        const float cxv = j ? A.y : A.x;
        const float cyv = j ? A.w : A.z;
        const float czv = j ? B.y : B.x;
        const float ddx = px - cxv;
        const float ddy = py - cyv;
        const float ddz = pz - czv;
        float nrm = sqrtf(((ddx * ddx) + (ddy * ddy)) + (ddz * ddz));
        nrm = fmaxf(nrm, 1e-12f);
        const float nx = active ? (ddx / nrm) : 0.0f;
        const float ny = active ? (ddy / nrm) : 0.0f;
        const float nz = active ? (ddz / nrm) : 0.0f;
        px = px + (nx * 1e-5f);
        py = py + (ny * 1e-5f);
        pz = pz + (nz * 1e-5f);

        float* outp = out;                 // p: 3*NRAYS
        float* outn = out + NRAYS * 3;     // n: 3*NRAYS
        float* outd = out + NRAYS * 6;     // best_dists: NRAYS
        float* outa = out + NRAYS * 7;     // out_active: NRAYS

        outp[r * 3 + 0] = px;
        outp[r * 3 + 1] = py;
        outp[r * 3 + 2] = pz;
        outn[r * 3 + 0] = nx;
        outn[r * 3 + 1] = ny;
        outn[r * 3 + 2] = nz;
        outd[r] = best;
        outa[r] = active ? 1.0f : 0.0f;
    }
}

extern "C" void kernel_launch(void* const* d_in, const int* in_sizes, int n_in,
                              void* d_out, int out_size, void* d_ws, size_t ws_size,
                              hipStream_t stream) {
    const float* rays    = (const float*)d_in[0];
    const float* centers = (const float*)d_in[1];
    const float* radii   = (const float*)d_in[2];
    float* out = (float*)d_out;

    dim3 grid(NBLK);     // 1024 blocks
    dim3 block(TPB);     // 256 threads
    hipLaunchKernelGGL(sphere_kernel, grid, block, 0, stream,
                       rays, centers, radii, out);
}